// Round 3
// baseline (211.523 us; speedup 1.0000x reference)
//
#include <hip/hip_runtime.h>
#include <hip/hip_bf16.h>

// FraudGNN: 2-layer GraphSAGE (mean aggr) + linear head.
// N=100000, E=1600000, feat 48 -> 32 -> 16 -> 2. fp32 in/out, int edge_index.
//
// R12: de-fuse K1. Two rounds of lin2 rewrites regressed (R10: forced
// launch_bounds -> scratch spill, 440us; R11: dual-acc LDS-operand form ->
// VGPR 232, 74us). lin2 reverts VERBATIM to R9's form (VGPR 108, ~50us
// fused). The fusion itself was also a problem: one kernel = one register
// allocation for both branches, so lin2's VGPR throttled the bucket branch.
// Now:
//  lin2_kernel:    R9 lin2 body, own launch, own 108-VGPR allocation.
//  bucket1_kernel: R11 sweep body (int4 loads, single cursor), own launch,
//                  low VGPR -> high occupancy.
// Also diagnostic: smaller per-dispatch durations let the true heavyweight
// among {bucket1,K2,K3,K4} (together ~130us, never yet profiled) surface in
// the top-5 counter rows next round.
//  K2: 1024 threads/block.   K3/K4: prefetch chain, shh stride 65.

constexpr int NN  = 100000;
constexpr int NE  = 1600000;
constexpr int NCH = (NN + 255) / 256;      // 391 lin2 blocks (256 nodes each)
constexpr int NB  = 391;                   // buckets = dst >> 8
constexpr int CAP = 4608;                  // per-bucket capacity (mean 4092, +8 sigma)
constexpr int SEG = CAP + 3 * 256;         // 5376: worst-case padded bucket footprint
constexpr int T1  = 2048;                  // edges per bucket1 block
constexpr int NB1 = (NE + T1 - 1) / T1;    // 782 bucket1 blocks

__device__ __forceinline__ float bl(unsigned u) { return __uint_as_float(u << 16); }
__device__ __forceinline__ float bh(unsigned u) { return __uint_as_float(u & 0xffff0000u); }
__device__ __forceinline__ unsigned f2b(float x) {
    unsigned u = __float_as_uint(x);
    return (u + 0x7fffu + ((u >> 16) & 1u)) >> 16;
}
__device__ __forceinline__ unsigned pack2(float a, float b) {
    return f2b(a) | (f2b(b) << 16);
}

__device__ __forceinline__ int wave_incl_scan(int v, int lane) {
#pragma unroll
    for (int d = 1; d < 64; d <<= 1) {
        int t = __shfl_up(v, d, 64);
        if (lane >= d) v += t;
    }
    return v;
}

// ---- lin2: P = X@Wl, R = X@Wr (bf16 rows), + zero row at NN ----------------
// R9's exact structure: xr[48] + accp[32] + accr[32], VGPR ~108, no bounds.
__global__ __launch_bounds__(256) void lin2_kernel(
    const float* __restrict__ X,
    const float* __restrict__ Wl,
    const float* __restrict__ Wr,
    __hip_bfloat16* __restrict__ P, __hip_bfloat16* __restrict__ R)
{
    __shared__ float sW[2][48 * 32];            // 12 KB
    for (int i = threadIdx.x; i < 48 * 32; i += 256) {
        sW[0][i] = Wl[i];
        sW[1][i] = Wr[i];
    }
    __syncthreads();
    int n = blockIdx.x * 256 + threadIdx.x;
    if (n > NN) return;
    if (n == NN) {                               // zero row (CSR pad target)
        uint4 z = make_uint4(0, 0, 0, 0);
        uint4* pp = reinterpret_cast<uint4*>(P + (size_t)NN * 32);
#pragma unroll
        for (int i = 0; i < 4; ++i) pp[i] = z;
        return;
    }
    float xr[48];
    const float4* xp = reinterpret_cast<const float4*>(X + (size_t)n * 48);
#pragma unroll
    for (int i = 0; i < 12; ++i) {
        float4 u = xp[i];
        xr[i*4+0] = u.x; xr[i*4+1] = u.y; xr[i*4+2] = u.z; xr[i*4+3] = u.w;
    }
    float accp[32], accr[32];
#pragma unroll
    for (int j = 0; j < 32; ++j) { accp[j] = 0.f; accr[j] = 0.f; }
#pragma unroll
    for (int k = 0; k < 48; ++k) {
        float xk = xr[k];
#pragma unroll
        for (int j = 0; j < 32; ++j) {
            accp[j] += xk * sW[0][k * 32 + j];
            accr[j] += xk * sW[1][k * 32 + j];
        }
    }
    uint4* pp = reinterpret_cast<uint4*>(P + (size_t)n * 32);
    uint4* rp = reinterpret_cast<uint4*>(R + (size_t)n * 32);
#pragma unroll
    for (int i = 0; i < 4; ++i) {
        uint4 u, v;
        u.x = pack2(accp[i*8+0], accp[i*8+1]); u.y = pack2(accp[i*8+2], accp[i*8+3]);
        u.z = pack2(accp[i*8+4], accp[i*8+5]); u.w = pack2(accp[i*8+6], accp[i*8+7]);
        v.x = pack2(accr[i*8+0], accr[i*8+1]); v.y = pack2(accr[i*8+2], accr[i*8+3]);
        v.z = pack2(accr[i*8+4], accr[i*8+5]); v.w = pack2(accr[i*8+6], accr[i*8+7]);
        pp[i] = u;
        rp[i] = v;
    }
}

// ---- bucket1: coarse sort edges by dst>>8 (own launch, low VGPR) -----------
__global__ __launch_bounds__(256) void bucket1_kernel(
    const int* __restrict__ ei,
    int* __restrict__ bsize, unsigned* __restrict__ bbuf)
{
    __shared__ int hist[NB], base[NB];          // 3.1 KB
    __shared__ int s_any;
    if (threadIdx.x == 0) s_any = 0;
    for (int i = threadIdx.x; i < NB; i += 256) hist[i] = 0;
    __syncthreads();
    // self-detect edge_index layout: int64 -> odd words all zero
    int dv = 0;
    for (int i = threadIdx.x; i < 2048; i += 256) dv |= ei[2 * i + 1];
    if (dv != 0) atomicOr(&s_any, 1);
    __syncthreads();
    const bool i64 = (s_any == 0);
    const int e0 = blockIdx.x * T1;

    // per-edge visitor sweep over this block's T1 edges, int4-vectorized
    auto sweep = [&](auto&& f) {
        if (i64) {
            const int4* sp = reinterpret_cast<const int4*>(ei) + (e0 >> 1);
            const int4* dp = reinterpret_cast<const int4*>(ei) + ((NE + e0) >> 1);
#pragma unroll
            for (int it = 0; it < 4; ++it) {
                int p = it * 256 + threadIdx.x;  // pair index
                int e = e0 + 2 * p;
                if (e + 2 <= NE) {
                    int4 s4 = sp[p], d4 = dp[p]; // (lo,hi,lo,hi)
                    f(s4.x, d4.x);
                    f(s4.z, d4.z);
                } else {
                    for (int e2 = e; e2 < NE && e2 < e + 2; ++e2)
                        f(ei[(size_t)e2 << 1], ei[(size_t)(NE + e2) << 1]);
                }
            }
        } else {
            const int4* sp = reinterpret_cast<const int4*>(ei) + (e0 >> 2);
            const int4* dp = reinterpret_cast<const int4*>(ei) + ((NE + e0) >> 2);
#pragma unroll
            for (int it = 0; it < 2; ++it) {
                int q = it * 256 + threadIdx.x;  // quad index
                int e = e0 + 4 * q;
                if (e + 4 <= NE) {
                    int4 s4 = sp[q], d4 = dp[q];
                    f(s4.x, d4.x);
                    f(s4.y, d4.y);
                    f(s4.z, d4.z);
                    f(s4.w, d4.w);
                } else {
                    for (int e2 = e; e2 < NE && e2 < e + 4; ++e2)
                        f(ei[e2], ei[NE + e2]);
                }
            }
        }
    };

    // phase 1: LDS histogram
    sweep([&](int s, int d) {
        if ((unsigned)s < (unsigned)NN && (unsigned)d < (unsigned)NN)
            atomicAdd(&hist[d >> 8], 1);
    });
    __syncthreads();
    // phase 2: reserve global ranges; base[] becomes the allocator cursor
    for (int b = threadIdx.x; b < NB; b += 256) {
        int h = hist[b];
        base[b] = h ? atomicAdd(&bsize[b], h) : 0;
    }
    __syncthreads();
    // phase 3: scatter (re-reads ei from hot L2; no reg staging)
    sweep([&](int s, int d) {
        if ((unsigned)s < (unsigned)NN && (unsigned)d < (unsigned)NN) {
            int bk = d >> 8;
            int pos = atomicAdd(&base[bk], 1);
            if (pos < CAP)
                bbuf[(size_t)bk * CAP + pos] =
                    ((unsigned)s << 8) | (unsigned)(d & 255);
        }
    });
}

// ---- K2: per-bucket CSR fill into fixed region b*SEG, x4-padded segments ----
__global__ __launch_bounds__(1024) void k2_kernel(
    const int* __restrict__ bsize, const unsigned* __restrict__ bbuf,
    int* __restrict__ deg, int* __restrict__ rowstart, int* __restrict__ csr_src)
{
    __shared__ int ldeg[256], lcur[256], ws[4];
    int b = blockIdx.x, t = threadIdx.x;
    int bs = b * SEG;                       // fixed region: no cross-bucket coupling

    int S = min(bsize[b], CAP);
    const unsigned* bp = bbuf + (size_t)b * CAP;
    if (t < 256) ldeg[t] = 0;
    __syncthreads();
    for (int i = t; i < S; i += 1024)
        atomicAdd(&ldeg[bp[i] & 255u], 1);
    __syncthreads();

    int v = 0, pv = 0, incl = 0, excl = 0;
    if (t < 256) {
        v  = ldeg[t];
        pv = (v + 3) & ~3;                  // padded per-node length
        incl = wave_incl_scan(pv, t & 63);
        if ((t & 63) == 63) ws[t >> 6] = incl;
    }
    __syncthreads();
    if (t < 256) {
        int off = 0, wid = t >> 6;
#pragma unroll
        for (int w = 0; w < 3; ++w)
            if (wid > w) off += ws[w];
        excl = off + incl - pv;             // <= S + 3*256 - pv <= SEG - pv
        int node = (b << 8) + t;
        if (node < NN) {
            deg[node] = v;
            rowstart[node] = bs + excl;     // 4-aligned (bs, excl both x4)
        }
        lcur[t] = excl;
    }
    __syncthreads();

    for (int i = t; i < S; i += 1024) {
        unsigned pk = bp[i];
        int pos = atomicAdd(&lcur[pk & 255u], 1);
        csr_src[bs + pos] = (int)(pk >> 8);
    }
    // pad tail of own node's segment with zero-row id (disjoint from fills)
    if (t < 256)
        for (int p = excl + v; p < excl + pv; ++p)
            csr_src[bs + p] = NN;
}

// ---- K3: layer1 gather (unroll-4, int4 idx) + update + layer2 projections ---
__global__ __launch_bounds__(256) void gather1f_kernel(
    const int* __restrict__ rowstart, const int* __restrict__ deg,
    const int* __restrict__ csr_src,
    const __hip_bfloat16* __restrict__ p1,     // [N+1,32] (row NN = 0)
    const __hip_bfloat16* __restrict__ r1,     // [N,32]
    const float* __restrict__ b1,              // [32]
    const float* __restrict__ W2l,             // [32,16]
    const float* __restrict__ W2r,             // [32,16]
    __hip_bfloat16* __restrict__ P2,           // [N+1,16] (row NN = 0)
    __hip_bfloat16* __restrict__ R2)           // [N+1,16]
{
    __shared__ float sW2l[32 * 16], sW2r[32 * 16], sb1[32];
    __shared__ float shh[32 * 65];             // h exchange, stride 65 (no conflict)
    int t = threadIdx.x;
    for (int i = t; i < 32 * 16; i += 256) { sW2l[i] = W2l[i]; sW2r[i] = W2r[i]; }
    if (t < 32) sb1[t] = b1[t];
    __syncthreads();

    int loc = t >> 2, c = t & 3;
    int n = blockIdx.x * 64 + loc;
    bool valid = n < NN;

    if (valid) {
        int start = rowstart[n], dn = deg[n];
        int pv4 = ((dn + 3) & ~3) >> 2;
        const uint4* prow = reinterpret_cast<const uint4*>(p1);
        const int4* cp4 = reinterpret_cast<const int4*>(csr_src + start);
        uint4 r = reinterpret_cast<const uint4*>(r1)[(size_t)n * 4 + c]; // hoisted
        float acc[8];
#pragma unroll
        for (int j = 0; j < 8; ++j) acc[j] = 0.f;
        int4 s4 = cp4[0];                       // in-workspace even if pv4==0
        for (int k = 0; k < pv4; ++k) {         // 4 row fetches in flight
            int4 nx = cp4[k + 1];               // prefetch next quad (<=16B overread,
                                                // stays inside workspace; never used
                                                // as an index past the loop)
            uint4 a = prow[(size_t)s4.x * 4 + c];
            uint4 b = prow[(size_t)s4.y * 4 + c];
            uint4 d = prow[(size_t)s4.z * 4 + c];
            uint4 e = prow[(size_t)s4.w * 4 + c];
            acc[0] += bl(a.x) + bl(b.x) + bl(d.x) + bl(e.x);
            acc[1] += bh(a.x) + bh(b.x) + bh(d.x) + bh(e.x);
            acc[2] += bl(a.y) + bl(b.y) + bl(d.y) + bl(e.y);
            acc[3] += bh(a.y) + bh(b.y) + bh(d.y) + bh(e.y);
            acc[4] += bl(a.z) + bl(b.z) + bl(d.z) + bl(e.z);
            acc[5] += bh(a.z) + bh(b.z) + bh(d.z) + bh(e.z);
            acc[6] += bl(a.w) + bl(b.w) + bl(d.w) + bl(e.w);
            acc[7] += bh(a.w) + bh(b.w) + bh(d.w) + bh(e.w);
            s4 = nx;
        }
        float inv = 1.0f / fmaxf((float)dn, 1.0f);
        float rr[8] = { bl(r.x), bh(r.x), bl(r.y), bh(r.y),
                        bl(r.z), bh(r.z), bl(r.w), bh(r.w) };
#pragma unroll
        for (int j = 0; j < 8; ++j)
            shh[(c * 8 + j) * 65 + loc] = fmaxf(acc[j] * inv + rr[j] + sb1[c * 8 + j], 0.f);
    }
    __syncthreads();

    if (valid) {
        float accp[4], accr[4];
#pragma unroll
        for (int j = 0; j < 4; ++j) { accp[j] = 0.f; accr[j] = 0.f; }
#pragma unroll
        for (int k = 0; k < 32; ++k) {
            float hk = shh[k * 65 + loc];
#pragma unroll
            for (int j = 0; j < 4; ++j) {
                accp[j] += hk * sW2l[k * 16 + c * 4 + j];
                accr[j] += hk * sW2r[k * 16 + c * 4 + j];
            }
        }
        uint2 up, ur;
        up.x = pack2(accp[0], accp[1]); up.y = pack2(accp[2], accp[3]);
        ur.x = pack2(accr[0], accr[1]); ur.y = pack2(accr[2], accr[3]);
        reinterpret_cast<uint2*>(P2)[(size_t)n * 4 + c] = up;
        reinterpret_cast<uint2*>(R2)[(size_t)n * 4 + c] = ur;
    } else if (n == NN) {                       // zero row for layer-2 pads
        uint2 z = make_uint2(0, 0);
        reinterpret_cast<uint2*>(P2)[(size_t)NN * 4 + c] = z;
        reinterpret_cast<uint2*>(R2)[(size_t)NN * 4 + c] = z;
    }
}

// ---- K4: layer2 gather (unroll-4) fused with final head ---------------------
__global__ __launch_bounds__(256) void gather2_kernel(
    const int* __restrict__ rowstart, const int* __restrict__ deg,
    const int* __restrict__ csr_src,
    const __hip_bfloat16* __restrict__ P2,
    const __hip_bfloat16* __restrict__ R2,
    const float* __restrict__ b2,       // [16]
    const float* __restrict__ Wlin,     // [16,2]
    const float* __restrict__ blin,     // [2]
    float* __restrict__ out)            // [NN,2]
{
    __shared__ float sb[16], sW[32], sbl[2];
    if (threadIdx.x < 16) sb[threadIdx.x] = b2[threadIdx.x];
    else if (threadIdx.x < 48) sW[threadIdx.x - 16] = Wlin[threadIdx.x - 16];
    else if (threadIdx.x < 50) sbl[threadIdx.x - 48] = blin[threadIdx.x - 48];
    __syncthreads();
    int t = blockIdx.x * 256 + threadIdx.x;
    int n = t >> 1, c = t & 1;
    if (n >= NN) return;
    int start = rowstart[n], dn = deg[n];
    int pv4 = ((dn + 3) & ~3) >> 2;

    const uint4* prow = reinterpret_cast<const uint4*>(P2);
    const int4* cp4 = reinterpret_cast<const int4*>(csr_src + start);
    uint4 r = reinterpret_cast<const uint4*>(R2)[(size_t)n * 2 + c]; // hoisted
    float acc[8];
#pragma unroll
    for (int j = 0; j < 8; ++j) acc[j] = 0.f;
    int4 s4 = cp4[0];
    for (int k = 0; k < pv4; ++k) {
        int4 nx = cp4[k + 1];               // prefetch (in-workspace overread)
        uint4 a = prow[(size_t)s4.x * 2 + c];
        uint4 b = prow[(size_t)s4.y * 2 + c];
        uint4 d = prow[(size_t)s4.z * 2 + c];
        uint4 e = prow[(size_t)s4.w * 2 + c];
        acc[0] += bl(a.x) + bl(b.x) + bl(d.x) + bl(e.x);
        acc[1] += bh(a.x) + bh(b.x) + bh(d.x) + bh(e.x);
        acc[2] += bl(a.y) + bl(b.y) + bl(d.y) + bl(e.y);
        acc[3] += bh(a.y) + bh(b.y) + bh(d.y) + bh(e.y);
        acc[4] += bl(a.z) + bl(b.z) + bl(d.z) + bl(e.z);
        acc[5] += bh(a.z) + bh(b.z) + bh(d.z) + bh(e.z);
        acc[6] += bl(a.w) + bl(b.w) + bl(d.w) + bl(e.w);
        acc[7] += bh(a.w) + bh(b.w) + bh(d.w) + bh(e.w);
        s4 = nx;
    }
    float inv = 1.0f / fmaxf((float)dn, 1.0f);
    float rr[8] = { bl(r.x), bh(r.x), bl(r.y), bh(r.y),
                    bl(r.z), bh(r.z), bl(r.w), bh(r.w) };
    float o0 = 0.f, o1 = 0.f;
#pragma unroll
    for (int j = 0; j < 8; ++j) {
        int kk = c * 8 + j;
        float hv = fmaxf(acc[j] * inv + rr[j] + sb[kk], 0.f);
        o0 += hv * sW[kk * 2];
        o1 += hv * sW[kk * 2 + 1];
    }
    o0 += __shfl_xor(o0, 1, 64);
    o1 += __shfl_xor(o1, 1, 64);
    if (c == 0)
        reinterpret_cast<float2*>(out)[n] = make_float2(o0 + sbl[0], o1 + sbl[1]);
}

extern "C" void kernel_launch(void* const* d_in, const int* in_sizes, int n_in,
                              void* d_out, int out_size, void* d_ws, size_t ws_size,
                              hipStream_t stream)
{
    const float* x    = (const float*)d_in[0];
    const int*   ei   = (const int*)d_in[1];
    const float* W1l  = (const float*)d_in[2];
    const float* W1r  = (const float*)d_in[3];
    const float* b1   = (const float*)d_in[4];
    const float* W2l  = (const float*)d_in[5];
    const float* W2r  = (const float*)d_in[6];
    const float* b2   = (const float*)d_in[7];
    const float* Wlin = (const float*)d_in[8];
    const float* blin = (const float*)d_in[9];
    float* out = (float*)d_out;

    // ---- workspace layout (bytes; ws_size = 256 MiB) ----
    char* wsb = (char*)d_ws;
    int*      bsize    = (int*)(wsb + 64);              // int[NB]
    int*      deg      = (int*)(wsb + 4096);            // int[N]
    int*      rowstart = (int*)(wsb + 404096);          // int[N]
    int*      csr_src  = (int*)(wsb + 804096);          // int[NB*SEG] 8.41 MB
    unsigned* bbuf     = (unsigned*)(wsb + 9300000);    // u32[NB*CAP] 7.21 MB
    __hip_bfloat16* p1 = (__hip_bfloat16*)(wsb + 16600000); // bf16[N+1,32]
    __hip_bfloat16* r1 = (__hip_bfloat16*)(wsb + 23100000); // bf16[N,32]
    __hip_bfloat16* p2 = (__hip_bfloat16*)(wsb + 29600000); // bf16[N+1,16]
    __hip_bfloat16* r2 = (__hip_bfloat16*)(wsb + 32900000); // bf16[N+1,16]

    dim3 blk(256);

    hipMemsetAsync(bsize, 0, NB * sizeof(int), stream);
    bucket1_kernel<<<NB1, blk, 0, stream>>>(ei, bsize, bbuf);
    lin2_kernel<<<NCH, blk, 0, stream>>>(x, W1l, W1r, p1, r1);
    k2_kernel<<<NB, dim3(1024), 0, stream>>>(bsize, bbuf, deg, rowstart, csr_src);
    gather1f_kernel<<<(NN + 1 + 63) / 64, blk, 0, stream>>>(
        rowstart, deg, csr_src, p1, r1, b1, W2l, W2r, p2, r2);
    gather2_kernel<<<(NN * 2 + 255) / 256, blk, 0, stream>>>(
        rowstart, deg, csr_src, p2, r2, b2, Wlin, blin, out);
}

// Round 4
// 181.813 us; speedup vs baseline: 1.1634x; 1.1634x over previous
//
#include <hip/hip_runtime.h>
#include <hip/hip_bf16.h>

// FraudGNN: 2-layer GraphSAGE (mean aggr) + linear head.
// N=100000, E=1600000, feat 48 -> 32 -> 16 -> 2. fp32 in/out, int edge_index.
//
// R13 = re-fuse K1 (R9 structure) + keep R12's K2/K3/K4.
// Evidence trail:
//  - R12 de-fused K1: lin2 alone = 84-105us (391 blocks, latency-exposed,
//    HBM 2.7%/VALU 9%/Occ 16%) vs 50us for the R9 FUSED lin2+bucket1 -> the
//    782 bucket blocks co-resident with lin2 were hiding its stalls. Same-
//    stream kernels serialize, so fusion is the only way to get that overlap.
//  - R12 subtraction: k2+g1+g2 dropped from ~137us (R9) to <=~95us with the
//    K2-1024-thread + K3/K4 prefetch/stride-65 changes -> keep them.
//  - lin2 body itself: 3 rewrites (R10 spill 440us, R11 VGPR-232 74us) all
//    lost to R9's xr[48]+acc[64] form -> revert verbatim, never force
//    launch_bounds min-waves on it.

constexpr int NN  = 100000;
constexpr int NE  = 1600000;
constexpr int NCH = (NN + 255) / 256;      // 391 lin2 chunks (256 nodes each)
constexpr int NB  = 391;                   // buckets = dst >> 8
constexpr int CAP = 4608;                  // per-bucket capacity (mean 4092, +8 sigma)
constexpr int SEG = CAP + 3 * 256;         // 5376: worst-case padded bucket footprint
constexpr int T1  = 2048;                  // edges per bucket1 block
constexpr int NB1 = (NE + T1 - 1) / T1;    // 782 bucket1 blocks

__device__ __forceinline__ float bl(unsigned u) { return __uint_as_float(u << 16); }
__device__ __forceinline__ float bh(unsigned u) { return __uint_as_float(u & 0xffff0000u); }
__device__ __forceinline__ unsigned f2b(float x) {
    unsigned u = __float_as_uint(x);
    return (u + 0x7fffu + ((u >> 16) & 1u)) >> 16;
}
__device__ __forceinline__ unsigned pack2(float a, float b) {
    return f2b(a) | (f2b(b) << 16);
}

__device__ __forceinline__ int wave_incl_scan(int v, int lane) {
#pragma unroll
    for (int d = 1; d < 64; d <<= 1) {
        int t = __shfl_up(v, d, 64);
        if (lane >= d) v += t;
    }
    return v;
}

// ---- K1: lin2 (blocks [0,NCH)) || bucket1 (blocks [NCH, NCH+NB1)) ----------
__global__ __launch_bounds__(256) void k1_kernel(
    const float* __restrict__ X,
    const float* __restrict__ Wl,
    const float* __restrict__ Wr,
    const int*   __restrict__ ei,
    int* __restrict__ bsize, unsigned* __restrict__ bbuf,
    __hip_bfloat16* __restrict__ P, __hip_bfloat16* __restrict__ R)
{
    __shared__ float sW[2][48 * 32];            // 12 KB (lin part)
    __shared__ int hist[NB], base[NB];          // 3.1 KB (bucket part)
    __shared__ int s_any;

    if (blockIdx.x < NCH) {
        // -------- lin2: P = X@Wl, R = X@Wr, + zero row at NN (R9 verbatim) --
        for (int i = threadIdx.x; i < 48 * 32; i += 256) {
            sW[0][i] = Wl[i];
            sW[1][i] = Wr[i];
        }
        __syncthreads();
        int n = blockIdx.x * 256 + threadIdx.x;
        if (n > NN) return;
        if (n == NN) {                           // zero row (CSR pad target)
            uint4 z = make_uint4(0, 0, 0, 0);
            uint4* pp = reinterpret_cast<uint4*>(P + (size_t)NN * 32);
#pragma unroll
            for (int i = 0; i < 4; ++i) pp[i] = z;
            return;
        }
        float xr[48];
        const float4* xp = reinterpret_cast<const float4*>(X + (size_t)n * 48);
#pragma unroll
        for (int i = 0; i < 12; ++i) {
            float4 u = xp[i];
            xr[i*4+0] = u.x; xr[i*4+1] = u.y; xr[i*4+2] = u.z; xr[i*4+3] = u.w;
        }
        float accp[32], accr[32];
#pragma unroll
        for (int j = 0; j < 32; ++j) { accp[j] = 0.f; accr[j] = 0.f; }
#pragma unroll
        for (int k = 0; k < 48; ++k) {
            float xk = xr[k];
#pragma unroll
            for (int j = 0; j < 32; ++j) {
                accp[j] += xk * sW[0][k * 32 + j];
                accr[j] += xk * sW[1][k * 32 + j];
            }
        }
        uint4* pp = reinterpret_cast<uint4*>(P + (size_t)n * 32);
        uint4* rp = reinterpret_cast<uint4*>(R + (size_t)n * 32);
#pragma unroll
        for (int i = 0; i < 4; ++i) {
            uint4 u, v;
            u.x = pack2(accp[i*8+0], accp[i*8+1]); u.y = pack2(accp[i*8+2], accp[i*8+3]);
            u.z = pack2(accp[i*8+4], accp[i*8+5]); u.w = pack2(accp[i*8+6], accp[i*8+7]);
            v.x = pack2(accr[i*8+0], accr[i*8+1]); v.y = pack2(accr[i*8+2], accr[i*8+3]);
            v.z = pack2(accr[i*8+4], accr[i*8+5]); v.w = pack2(accr[i*8+6], accr[i*8+7]);
            pp[i] = u;
            rp[i] = v;
        }
    } else {
        // ---------------- bucket1: coarse sort edges by dst>>8 (R12 sweep) --
        if (threadIdx.x == 0) s_any = 0;
        for (int i = threadIdx.x; i < NB; i += 256) hist[i] = 0;
        __syncthreads();
        // self-detect edge_index layout: int64 -> odd words all zero
        int dv = 0;
        for (int i = threadIdx.x; i < 2048; i += 256) dv |= ei[2 * i + 1];
        if (dv != 0) atomicOr(&s_any, 1);
        __syncthreads();
        const bool i64 = (s_any == 0);
        const int e0 = (blockIdx.x - NCH) * T1;

        // per-edge visitor sweep over this block's T1 edges, int4-vectorized
        auto sweep = [&](auto&& f) {
            if (i64) {
                const int4* sp = reinterpret_cast<const int4*>(ei) + (e0 >> 1);
                const int4* dp = reinterpret_cast<const int4*>(ei) + ((NE + e0) >> 1);
#pragma unroll
                for (int it = 0; it < 4; ++it) {
                    int p = it * 256 + threadIdx.x;  // pair index
                    int e = e0 + 2 * p;
                    if (e + 2 <= NE) {
                        int4 s4 = sp[p], d4 = dp[p]; // (lo,hi,lo,hi)
                        f(s4.x, d4.x);
                        f(s4.z, d4.z);
                    } else {
                        for (int e2 = e; e2 < NE && e2 < e + 2; ++e2)
                            f(ei[(size_t)e2 << 1], ei[(size_t)(NE + e2) << 1]);
                    }
                }
            } else {
                const int4* sp = reinterpret_cast<const int4*>(ei) + (e0 >> 2);
                const int4* dp = reinterpret_cast<const int4*>(ei) + ((NE + e0) >> 2);
#pragma unroll
                for (int it = 0; it < 2; ++it) {
                    int q = it * 256 + threadIdx.x;  // quad index
                    int e = e0 + 4 * q;
                    if (e + 4 <= NE) {
                        int4 s4 = sp[q], d4 = dp[q];
                        f(s4.x, d4.x);
                        f(s4.y, d4.y);
                        f(s4.z, d4.z);
                        f(s4.w, d4.w);
                    } else {
                        for (int e2 = e; e2 < NE && e2 < e + 4; ++e2)
                            f(ei[e2], ei[NE + e2]);
                    }
                }
            }
        };

        // phase 1: LDS histogram
        sweep([&](int s, int d) {
            if ((unsigned)s < (unsigned)NN && (unsigned)d < (unsigned)NN)
                atomicAdd(&hist[d >> 8], 1);
        });
        __syncthreads();
        // phase 2: reserve global ranges; base[] becomes the allocator cursor
        for (int b = threadIdx.x; b < NB; b += 256) {
            int h = hist[b];
            base[b] = h ? atomicAdd(&bsize[b], h) : 0;
        }
        __syncthreads();
        // phase 3: scatter (re-reads ei from hot L2; no reg staging)
        sweep([&](int s, int d) {
            if ((unsigned)s < (unsigned)NN && (unsigned)d < (unsigned)NN) {
                int bk = d >> 8;
                int pos = atomicAdd(&base[bk], 1);
                if (pos < CAP)
                    bbuf[(size_t)bk * CAP + pos] =
                        ((unsigned)s << 8) | (unsigned)(d & 255);
            }
        });
    }
}

// ---- K2: per-bucket CSR fill into fixed region b*SEG, x4-padded segments ----
__global__ __launch_bounds__(1024) void k2_kernel(
    const int* __restrict__ bsize, const unsigned* __restrict__ bbuf,
    int* __restrict__ deg, int* __restrict__ rowstart, int* __restrict__ csr_src)
{
    __shared__ int ldeg[256], lcur[256], ws[4];
    int b = blockIdx.x, t = threadIdx.x;
    int bs = b * SEG;                       // fixed region: no cross-bucket coupling

    int S = min(bsize[b], CAP);
    const unsigned* bp = bbuf + (size_t)b * CAP;
    if (t < 256) ldeg[t] = 0;
    __syncthreads();
    for (int i = t; i < S; i += 1024)
        atomicAdd(&ldeg[bp[i] & 255u], 1);
    __syncthreads();

    int v = 0, pv = 0, incl = 0, excl = 0;
    if (t < 256) {
        v  = ldeg[t];
        pv = (v + 3) & ~3;                  // padded per-node length
        incl = wave_incl_scan(pv, t & 63);
        if ((t & 63) == 63) ws[t >> 6] = incl;
    }
    __syncthreads();
    if (t < 256) {
        int off = 0, wid = t >> 6;
#pragma unroll
        for (int w = 0; w < 3; ++w)
            if (wid > w) off += ws[w];
        excl = off + incl - pv;             // <= S + 3*256 - pv <= SEG - pv
        int node = (b << 8) + t;
        if (node < NN) {
            deg[node] = v;
            rowstart[node] = bs + excl;     // 4-aligned (bs, excl both x4)
        }
        lcur[t] = excl;
    }
    __syncthreads();

    for (int i = t; i < S; i += 1024) {
        unsigned pk = bp[i];
        int pos = atomicAdd(&lcur[pk & 255u], 1);
        csr_src[bs + pos] = (int)(pk >> 8);
    }
    // pad tail of own node's segment with zero-row id (disjoint from fills)
    if (t < 256)
        for (int p = excl + v; p < excl + pv; ++p)
            csr_src[bs + p] = NN;
}

// ---- K3: layer1 gather (unroll-4, int4 idx) + update + layer2 projections ---
__global__ __launch_bounds__(256) void gather1f_kernel(
    const int* __restrict__ rowstart, const int* __restrict__ deg,
    const int* __restrict__ csr_src,
    const __hip_bfloat16* __restrict__ p1,     // [N+1,32] (row NN = 0)
    const __hip_bfloat16* __restrict__ r1,     // [N,32]
    const float* __restrict__ b1,              // [32]
    const float* __restrict__ W2l,             // [32,16]
    const float* __restrict__ W2r,             // [32,16]
    __hip_bfloat16* __restrict__ P2,           // [N+1,16] (row NN = 0)
    __hip_bfloat16* __restrict__ R2)           // [N+1,16]
{
    __shared__ float sW2l[32 * 16], sW2r[32 * 16], sb1[32];
    __shared__ float shh[32 * 65];             // h exchange, stride 65 (no conflict)
    int t = threadIdx.x;
    for (int i = t; i < 32 * 16; i += 256) { sW2l[i] = W2l[i]; sW2r[i] = W2r[i]; }
    if (t < 32) sb1[t] = b1[t];
    __syncthreads();

    int loc = t >> 2, c = t & 3;
    int n = blockIdx.x * 64 + loc;
    bool valid = n < NN;

    if (valid) {
        int start = rowstart[n], dn = deg[n];
        int pv4 = ((dn + 3) & ~3) >> 2;
        const uint4* prow = reinterpret_cast<const uint4*>(p1);
        const int4* cp4 = reinterpret_cast<const int4*>(csr_src + start);
        uint4 r = reinterpret_cast<const uint4*>(r1)[(size_t)n * 4 + c]; // hoisted
        float acc[8];
#pragma unroll
        for (int j = 0; j < 8; ++j) acc[j] = 0.f;
        int4 s4 = cp4[0];                       // in-workspace even if pv4==0
        for (int k = 0; k < pv4; ++k) {         // 4 row fetches in flight
            int4 nx = cp4[k + 1];               // prefetch next quad (<=16B overread,
                                                // stays inside workspace; never used
                                                // as an index past the loop)
            uint4 a = prow[(size_t)s4.x * 4 + c];
            uint4 b = prow[(size_t)s4.y * 4 + c];
            uint4 d = prow[(size_t)s4.z * 4 + c];
            uint4 e = prow[(size_t)s4.w * 4 + c];
            acc[0] += bl(a.x) + bl(b.x) + bl(d.x) + bl(e.x);
            acc[1] += bh(a.x) + bh(b.x) + bh(d.x) + bh(e.x);
            acc[2] += bl(a.y) + bl(b.y) + bl(d.y) + bl(e.y);
            acc[3] += bh(a.y) + bh(b.y) + bh(d.y) + bh(e.y);
            acc[4] += bl(a.z) + bl(b.z) + bl(d.z) + bl(e.z);
            acc[5] += bh(a.z) + bh(b.z) + bh(d.z) + bh(e.z);
            acc[6] += bl(a.w) + bl(b.w) + bl(d.w) + bl(e.w);
            acc[7] += bh(a.w) + bh(b.w) + bh(d.w) + bh(e.w);
            s4 = nx;
        }
        float inv = 1.0f / fmaxf((float)dn, 1.0f);
        float rr[8] = { bl(r.x), bh(r.x), bl(r.y), bh(r.y),
                        bl(r.z), bh(r.z), bl(r.w), bh(r.w) };
#pragma unroll
        for (int j = 0; j < 8; ++j)
            shh[(c * 8 + j) * 65 + loc] = fmaxf(acc[j] * inv + rr[j] + sb1[c * 8 + j], 0.f);
    }
    __syncthreads();

    if (valid) {
        float accp[4], accr[4];
#pragma unroll
        for (int j = 0; j < 4; ++j) { accp[j] = 0.f; accr[j] = 0.f; }
#pragma unroll
        for (int k = 0; k < 32; ++k) {
            float hk = shh[k * 65 + loc];
#pragma unroll
            for (int j = 0; j < 4; ++j) {
                accp[j] += hk * sW2l[k * 16 + c * 4 + j];
                accr[j] += hk * sW2r[k * 16 + c * 4 + j];
            }
        }
        uint2 up, ur;
        up.x = pack2(accp[0], accp[1]); up.y = pack2(accp[2], accp[3]);
        ur.x = pack2(accr[0], accr[1]); ur.y = pack2(accr[2], accr[3]);
        reinterpret_cast<uint2*>(P2)[(size_t)n * 4 + c] = up;
        reinterpret_cast<uint2*>(R2)[(size_t)n * 4 + c] = ur;
    } else if (n == NN) {                       // zero row for layer-2 pads
        uint2 z = make_uint2(0, 0);
        reinterpret_cast<uint2*>(P2)[(size_t)NN * 4 + c] = z;
        reinterpret_cast<uint2*>(R2)[(size_t)NN * 4 + c] = z;
    }
}

// ---- K4: layer2 gather (unroll-4) fused with final head ---------------------
__global__ __launch_bounds__(256) void gather2_kernel(
    const int* __restrict__ rowstart, const int* __restrict__ deg,
    const int* __restrict__ csr_src,
    const __hip_bfloat16* __restrict__ P2,
    const __hip_bfloat16* __restrict__ R2,
    const float* __restrict__ b2,       // [16]
    const float* __restrict__ Wlin,     // [16,2]
    const float* __restrict__ blin,     // [2]
    float* __restrict__ out)            // [NN,2]
{
    __shared__ float sb[16], sW[32], sbl[2];
    if (threadIdx.x < 16) sb[threadIdx.x] = b2[threadIdx.x];
    else if (threadIdx.x < 48) sW[threadIdx.x - 16] = Wlin[threadIdx.x - 16];
    else if (threadIdx.x < 50) sbl[threadIdx.x - 48] = blin[threadIdx.x - 48];
    __syncthreads();
    int t = blockIdx.x * 256 + threadIdx.x;
    int n = t >> 1, c = t & 1;
    if (n >= NN) return;
    int start = rowstart[n], dn = deg[n];
    int pv4 = ((dn + 3) & ~3) >> 2;

    const uint4* prow = reinterpret_cast<const uint4*>(P2);
    const int4* cp4 = reinterpret_cast<const int4*>(csr_src + start);
    uint4 r = reinterpret_cast<const uint4*>(R2)[(size_t)n * 2 + c]; // hoisted
    float acc[8];
#pragma unroll
    for (int j = 0; j < 8; ++j) acc[j] = 0.f;
    int4 s4 = cp4[0];
    for (int k = 0; k < pv4; ++k) {
        int4 nx = cp4[k + 1];               // prefetch (in-workspace overread)
        uint4 a = prow[(size_t)s4.x * 2 + c];
        uint4 b = prow[(size_t)s4.y * 2 + c];
        uint4 d = prow[(size_t)s4.z * 2 + c];
        uint4 e = prow[(size_t)s4.w * 2 + c];
        acc[0] += bl(a.x) + bl(b.x) + bl(d.x) + bl(e.x);
        acc[1] += bh(a.x) + bh(b.x) + bh(d.x) + bh(e.x);
        acc[2] += bl(a.y) + bl(b.y) + bl(d.y) + bl(e.y);
        acc[3] += bh(a.y) + bh(b.y) + bh(d.y) + bh(e.y);
        acc[4] += bl(a.z) + bl(b.z) + bl(d.z) + bl(e.z);
        acc[5] += bh(a.z) + bh(b.z) + bh(d.z) + bh(e.z);
        acc[6] += bl(a.w) + bl(b.w) + bl(d.w) + bl(e.w);
        acc[7] += bh(a.w) + bh(b.w) + bh(d.w) + bh(e.w);
        s4 = nx;
    }
    float inv = 1.0f / fmaxf((float)dn, 1.0f);
    float rr[8] = { bl(r.x), bh(r.x), bl(r.y), bh(r.y),
                    bl(r.z), bh(r.z), bl(r.w), bh(r.w) };
    float o0 = 0.f, o1 = 0.f;
#pragma unroll
    for (int j = 0; j < 8; ++j) {
        int kk = c * 8 + j;
        float hv = fmaxf(acc[j] * inv + rr[j] + sb[kk], 0.f);
        o0 += hv * sW[kk * 2];
        o1 += hv * sW[kk * 2 + 1];
    }
    o0 += __shfl_xor(o0, 1, 64);
    o1 += __shfl_xor(o1, 1, 64);
    if (c == 0)
        reinterpret_cast<float2*>(out)[n] = make_float2(o0 + sbl[0], o1 + sbl[1]);
}

extern "C" void kernel_launch(void* const* d_in, const int* in_sizes, int n_in,
                              void* d_out, int out_size, void* d_ws, size_t ws_size,
                              hipStream_t stream)
{
    const float* x    = (const float*)d_in[0];
    const int*   ei   = (const int*)d_in[1];
    const float* W1l  = (const float*)d_in[2];
    const float* W1r  = (const float*)d_in[3];
    const float* b1   = (const float*)d_in[4];
    const float* W2l  = (const float*)d_in[5];
    const float* W2r  = (const float*)d_in[6];
    const float* b2   = (const float*)d_in[7];
    const float* Wlin = (const float*)d_in[8];
    const float* blin = (const float*)d_in[9];
    float* out = (float*)d_out;

    // ---- workspace layout (bytes; ws_size = 256 MiB) ----
    char* wsb = (char*)d_ws;
    int*      bsize    = (int*)(wsb + 64);              // int[NB]
    int*      deg      = (int*)(wsb + 4096);            // int[N]
    int*      rowstart = (int*)(wsb + 404096);          // int[N]
    int*      csr_src  = (int*)(wsb + 804096);          // int[NB*SEG] 8.41 MB
    unsigned* bbuf     = (unsigned*)(wsb + 9300000);    // u32[NB*CAP] 7.21 MB
    __hip_bfloat16* p1 = (__hip_bfloat16*)(wsb + 16600000); // bf16[N+1,32]
    __hip_bfloat16* r1 = (__hip_bfloat16*)(wsb + 23100000); // bf16[N,32]
    __hip_bfloat16* p2 = (__hip_bfloat16*)(wsb + 29600000); // bf16[N+1,16]
    __hip_bfloat16* r2 = (__hip_bfloat16*)(wsb + 32900000); // bf16[N+1,16]

    dim3 blk(256);

    hipMemsetAsync(bsize, 0, NB * sizeof(int), stream);
    k1_kernel<<<NCH + NB1, blk, 0, stream>>>(x, W1l, W1r, ei, bsize, bbuf, p1, r1);
    k2_kernel<<<NB, dim3(1024), 0, stream>>>(bsize, bbuf, deg, rowstart, csr_src);
    gather1f_kernel<<<(NN + 1 + 63) / 64, blk, 0, stream>>>(
        rowstart, deg, csr_src, p1, r1, b1, W2l, W2r, p2, r2);
    gather2_kernel<<<(NN * 2 + 255) / 256, blk, 0, stream>>>(
        rowstart, deg, csr_src, p2, r2, b2, Wlin, blin, out);
}

// Round 5
// 175.859 us; speedup vs baseline: 1.2028x; 1.0339x over previous
//
#include <hip/hip_runtime.h>
#include <hip/hip_bf16.h>

// FraudGNN: 2-layer GraphSAGE (mean aggr) + linear head.
// N=100000, E=1600000, feat 48 -> 32 -> 16 -> 2. fp32 in/out, int edge_index.
//
// R14 = R13 + unroll-2 gather loops (g1/g2): 8 independent row-fetches in
// flight per lane (was 4), idx prefetch 2-ahead. Rationale: k1=46.5us leaves
// ~135us in k2+g1+g2 (all <45.5us each, absent from top-5). g1's BW floor is
// ~15-20us (102 MB of 64B-row gathers from a 6.4MB L2/L3-resident table) so
// if it runs 35-45us it is latency-bound -> deeper MLP attacks it directly.
// k1/k2 untouched (k1 is the 4-round-verified fused form, VGPR 108).
// Evidence trail: R10 spill (440us), R11 VGPR-232 (74us), R12 de-fuse
// (lin2 alone 84-105us) -> lin2 body frozen at R9 form, fused with bucket1.

constexpr int NN  = 100000;
constexpr int NE  = 1600000;
constexpr int NCH = (NN + 255) / 256;      // 391 lin2 chunks (256 nodes each)
constexpr int NB  = 391;                   // buckets = dst >> 8
constexpr int CAP = 4608;                  // per-bucket capacity (mean 4092, +8 sigma)
constexpr int SEG = CAP + 3 * 256;         // 5376: worst-case padded bucket footprint
constexpr int T1  = 2048;                  // edges per bucket1 block
constexpr int NB1 = (NE + T1 - 1) / T1;    // 782 bucket1 blocks

__device__ __forceinline__ float bl(unsigned u) { return __uint_as_float(u << 16); }
__device__ __forceinline__ float bh(unsigned u) { return __uint_as_float(u & 0xffff0000u); }
__device__ __forceinline__ unsigned f2b(float x) {
    unsigned u = __float_as_uint(x);
    return (u + 0x7fffu + ((u >> 16) & 1u)) >> 16;
}
__device__ __forceinline__ unsigned pack2(float a, float b) {
    return f2b(a) | (f2b(b) << 16);
}

__device__ __forceinline__ int wave_incl_scan(int v, int lane) {
#pragma unroll
    for (int d = 1; d < 64; d <<= 1) {
        int t = __shfl_up(v, d, 64);
        if (lane >= d) v += t;
    }
    return v;
}

// ---- K1: lin2 (blocks [0,NCH)) || bucket1 (blocks [NCH, NCH+NB1)) ----------
__global__ __launch_bounds__(256) void k1_kernel(
    const float* __restrict__ X,
    const float* __restrict__ Wl,
    const float* __restrict__ Wr,
    const int*   __restrict__ ei,
    int* __restrict__ bsize, unsigned* __restrict__ bbuf,
    __hip_bfloat16* __restrict__ P, __hip_bfloat16* __restrict__ R)
{
    __shared__ float sW[2][48 * 32];            // 12 KB (lin part)
    __shared__ int hist[NB], base[NB];          // 3.1 KB (bucket part)
    __shared__ int s_any;

    if (blockIdx.x < NCH) {
        // -------- lin2: P = X@Wl, R = X@Wr, + zero row at NN (R9 verbatim) --
        for (int i = threadIdx.x; i < 48 * 32; i += 256) {
            sW[0][i] = Wl[i];
            sW[1][i] = Wr[i];
        }
        __syncthreads();
        int n = blockIdx.x * 256 + threadIdx.x;
        if (n > NN) return;
        if (n == NN) {                           // zero row (CSR pad target)
            uint4 z = make_uint4(0, 0, 0, 0);
            uint4* pp = reinterpret_cast<uint4*>(P + (size_t)NN * 32);
#pragma unroll
            for (int i = 0; i < 4; ++i) pp[i] = z;
            return;
        }
        float xr[48];
        const float4* xp = reinterpret_cast<const float4*>(X + (size_t)n * 48);
#pragma unroll
        for (int i = 0; i < 12; ++i) {
            float4 u = xp[i];
            xr[i*4+0] = u.x; xr[i*4+1] = u.y; xr[i*4+2] = u.z; xr[i*4+3] = u.w;
        }
        float accp[32], accr[32];
#pragma unroll
        for (int j = 0; j < 32; ++j) { accp[j] = 0.f; accr[j] = 0.f; }
#pragma unroll
        for (int k = 0; k < 48; ++k) {
            float xk = xr[k];
#pragma unroll
            for (int j = 0; j < 32; ++j) {
                accp[j] += xk * sW[0][k * 32 + j];
                accr[j] += xk * sW[1][k * 32 + j];
            }
        }
        uint4* pp = reinterpret_cast<uint4*>(P + (size_t)n * 32);
        uint4* rp = reinterpret_cast<uint4*>(R + (size_t)n * 32);
#pragma unroll
        for (int i = 0; i < 4; ++i) {
            uint4 u, v;
            u.x = pack2(accp[i*8+0], accp[i*8+1]); u.y = pack2(accp[i*8+2], accp[i*8+3]);
            u.z = pack2(accp[i*8+4], accp[i*8+5]); u.w = pack2(accp[i*8+6], accp[i*8+7]);
            v.x = pack2(accr[i*8+0], accr[i*8+1]); v.y = pack2(accr[i*8+2], accr[i*8+3]);
            v.z = pack2(accr[i*8+4], accr[i*8+5]); v.w = pack2(accr[i*8+6], accr[i*8+7]);
            pp[i] = u;
            rp[i] = v;
        }
    } else {
        // ---------------- bucket1: coarse sort edges by dst>>8 (R12 sweep) --
        if (threadIdx.x == 0) s_any = 0;
        for (int i = threadIdx.x; i < NB; i += 256) hist[i] = 0;
        __syncthreads();
        // self-detect edge_index layout: int64 -> odd words all zero
        int dv = 0;
        for (int i = threadIdx.x; i < 2048; i += 256) dv |= ei[2 * i + 1];
        if (dv != 0) atomicOr(&s_any, 1);
        __syncthreads();
        const bool i64 = (s_any == 0);
        const int e0 = (blockIdx.x - NCH) * T1;

        // per-edge visitor sweep over this block's T1 edges, int4-vectorized
        auto sweep = [&](auto&& f) {
            if (i64) {
                const int4* sp = reinterpret_cast<const int4*>(ei) + (e0 >> 1);
                const int4* dp = reinterpret_cast<const int4*>(ei) + ((NE + e0) >> 1);
#pragma unroll
                for (int it = 0; it < 4; ++it) {
                    int p = it * 256 + threadIdx.x;  // pair index
                    int e = e0 + 2 * p;
                    if (e + 2 <= NE) {
                        int4 s4 = sp[p], d4 = dp[p]; // (lo,hi,lo,hi)
                        f(s4.x, d4.x);
                        f(s4.z, d4.z);
                    } else {
                        for (int e2 = e; e2 < NE && e2 < e + 2; ++e2)
                            f(ei[(size_t)e2 << 1], ei[(size_t)(NE + e2) << 1]);
                    }
                }
            } else {
                const int4* sp = reinterpret_cast<const int4*>(ei) + (e0 >> 2);
                const int4* dp = reinterpret_cast<const int4*>(ei) + ((NE + e0) >> 2);
#pragma unroll
                for (int it = 0; it < 2; ++it) {
                    int q = it * 256 + threadIdx.x;  // quad index
                    int e = e0 + 4 * q;
                    if (e + 4 <= NE) {
                        int4 s4 = sp[q], d4 = dp[q];
                        f(s4.x, d4.x);
                        f(s4.y, d4.y);
                        f(s4.z, d4.z);
                        f(s4.w, d4.w);
                    } else {
                        for (int e2 = e; e2 < NE && e2 < e + 4; ++e2)
                            f(ei[e2], ei[NE + e2]);
                    }
                }
            }
        };

        // phase 1: LDS histogram
        sweep([&](int s, int d) {
            if ((unsigned)s < (unsigned)NN && (unsigned)d < (unsigned)NN)
                atomicAdd(&hist[d >> 8], 1);
        });
        __syncthreads();
        // phase 2: reserve global ranges; base[] becomes the allocator cursor
        for (int b = threadIdx.x; b < NB; b += 256) {
            int h = hist[b];
            base[b] = h ? atomicAdd(&bsize[b], h) : 0;
        }
        __syncthreads();
        // phase 3: scatter (re-reads ei from hot L2; no reg staging)
        sweep([&](int s, int d) {
            if ((unsigned)s < (unsigned)NN && (unsigned)d < (unsigned)NN) {
                int bk = d >> 8;
                int pos = atomicAdd(&base[bk], 1);
                if (pos < CAP)
                    bbuf[(size_t)bk * CAP + pos] =
                        ((unsigned)s << 8) | (unsigned)(d & 255);
            }
        });
    }
}

// ---- K2: per-bucket CSR fill into fixed region b*SEG, x4-padded segments ----
__global__ __launch_bounds__(1024) void k2_kernel(
    const int* __restrict__ bsize, const unsigned* __restrict__ bbuf,
    int* __restrict__ deg, int* __restrict__ rowstart, int* __restrict__ csr_src)
{
    __shared__ int ldeg[256], lcur[256], ws[4];
    int b = blockIdx.x, t = threadIdx.x;
    int bs = b * SEG;                       // fixed region: no cross-bucket coupling

    int S = min(bsize[b], CAP);
    const unsigned* bp = bbuf + (size_t)b * CAP;
    if (t < 256) ldeg[t] = 0;
    __syncthreads();
    for (int i = t; i < S; i += 1024)
        atomicAdd(&ldeg[bp[i] & 255u], 1);
    __syncthreads();

    int v = 0, pv = 0, incl = 0, excl = 0;
    if (t < 256) {
        v  = ldeg[t];
        pv = (v + 3) & ~3;                  // padded per-node length
        incl = wave_incl_scan(pv, t & 63);
        if ((t & 63) == 63) ws[t >> 6] = incl;
    }
    __syncthreads();
    if (t < 256) {
        int off = 0, wid = t >> 6;
#pragma unroll
        for (int w = 0; w < 3; ++w)
            if (wid > w) off += ws[w];
        excl = off + incl - pv;             // <= S + 3*256 - pv <= SEG - pv
        int node = (b << 8) + t;
        if (node < NN) {
            deg[node] = v;
            rowstart[node] = bs + excl;     // 4-aligned (bs, excl both x4)
        }
        lcur[t] = excl;
    }
    __syncthreads();

    for (int i = t; i < S; i += 1024) {
        unsigned pk = bp[i];
        int pos = atomicAdd(&lcur[pk & 255u], 1);
        csr_src[bs + pos] = (int)(pk >> 8);
    }
    // pad tail of own node's segment with zero-row id (disjoint from fills)
    if (t < 256)
        for (int p = excl + v; p < excl + pv; ++p)
            csr_src[bs + p] = NN;
}

// ---- K3: layer1 gather (unroll-2x4, int4 idx) + update + layer2 projections -
__global__ __launch_bounds__(256) void gather1f_kernel(
    const int* __restrict__ rowstart, const int* __restrict__ deg,
    const int* __restrict__ csr_src,
    const __hip_bfloat16* __restrict__ p1,     // [N+1,32] (row NN = 0)
    const __hip_bfloat16* __restrict__ r1,     // [N,32]
    const float* __restrict__ b1,              // [32]
    const float* __restrict__ W2l,             // [32,16]
    const float* __restrict__ W2r,             // [32,16]
    __hip_bfloat16* __restrict__ P2,           // [N+1,16] (row NN = 0)
    __hip_bfloat16* __restrict__ R2)           // [N+1,16]
{
    __shared__ float sW2l[32 * 16], sW2r[32 * 16], sb1[32];
    __shared__ float shh[32 * 65];             // h exchange, stride 65 (no conflict)
    int t = threadIdx.x;
    for (int i = t; i < 32 * 16; i += 256) { sW2l[i] = W2l[i]; sW2r[i] = W2r[i]; }
    if (t < 32) sb1[t] = b1[t];
    __syncthreads();

    int loc = t >> 2, c = t & 3;
    int n = blockIdx.x * 64 + loc;
    bool valid = n < NN;

    if (valid) {
        int start = rowstart[n], dn = deg[n];
        int pv4 = ((dn + 3) & ~3) >> 2;
        const uint4* prow = reinterpret_cast<const uint4*>(p1);
        const int4* cp4 = reinterpret_cast<const int4*>(csr_src + start);
        uint4 r = reinterpret_cast<const uint4*>(r1)[(size_t)n * 4 + c]; // hoisted
        float acc[8];
#pragma unroll
        for (int j = 0; j < 8; ++j) acc[j] = 0.f;
        // unroll-2: 8 row-fetches in flight; idx prefetch 2-ahead.
        // Overreads (<=32B past segment end) stay inside workspace; any idx
        // actually consumed has k < pv4 (pad entries = NN -> zero row).
        int k = 0;
        int4 sA = cp4[0];
        int4 sB = cp4[1];
        for (; k + 1 < pv4; k += 2) {
            int4 nA = cp4[k + 2];
            int4 nB = cp4[k + 3];
            uint4 a = prow[(size_t)sA.x * 4 + c];
            uint4 b = prow[(size_t)sA.y * 4 + c];
            uint4 d = prow[(size_t)sA.z * 4 + c];
            uint4 e = prow[(size_t)sA.w * 4 + c];
            uint4 f = prow[(size_t)sB.x * 4 + c];
            uint4 g = prow[(size_t)sB.y * 4 + c];
            uint4 h = prow[(size_t)sB.z * 4 + c];
            uint4 m = prow[(size_t)sB.w * 4 + c];
            acc[0] += bl(a.x) + bl(b.x) + bl(d.x) + bl(e.x)
                    + bl(f.x) + bl(g.x) + bl(h.x) + bl(m.x);
            acc[1] += bh(a.x) + bh(b.x) + bh(d.x) + bh(e.x)
                    + bh(f.x) + bh(g.x) + bh(h.x) + bh(m.x);
            acc[2] += bl(a.y) + bl(b.y) + bl(d.y) + bl(e.y)
                    + bl(f.y) + bl(g.y) + bl(h.y) + bl(m.y);
            acc[3] += bh(a.y) + bh(b.y) + bh(d.y) + bh(e.y)
                    + bh(f.y) + bh(g.y) + bh(h.y) + bh(m.y);
            acc[4] += bl(a.z) + bl(b.z) + bl(d.z) + bl(e.z)
                    + bl(f.z) + bl(g.z) + bl(h.z) + bl(m.z);
            acc[5] += bh(a.z) + bh(b.z) + bh(d.z) + bh(e.z)
                    + bh(f.z) + bh(g.z) + bh(h.z) + bh(m.z);
            acc[6] += bl(a.w) + bl(b.w) + bl(d.w) + bl(e.w)
                    + bl(f.w) + bl(g.w) + bl(h.w) + bl(m.w);
            acc[7] += bh(a.w) + bh(b.w) + bh(d.w) + bh(e.w)
                    + bh(f.w) + bh(g.w) + bh(h.w) + bh(m.w);
            sA = nA; sB = nB;
        }
        if (k < pv4) {                          // odd tail: one quad
            uint4 a = prow[(size_t)sA.x * 4 + c];
            uint4 b = prow[(size_t)sA.y * 4 + c];
            uint4 d = prow[(size_t)sA.z * 4 + c];
            uint4 e = prow[(size_t)sA.w * 4 + c];
            acc[0] += bl(a.x) + bl(b.x) + bl(d.x) + bl(e.x);
            acc[1] += bh(a.x) + bh(b.x) + bh(d.x) + bh(e.x);
            acc[2] += bl(a.y) + bl(b.y) + bl(d.y) + bl(e.y);
            acc[3] += bh(a.y) + bh(b.y) + bh(d.y) + bh(e.y);
            acc[4] += bl(a.z) + bl(b.z) + bl(d.z) + bl(e.z);
            acc[5] += bh(a.z) + bh(b.z) + bh(d.z) + bh(e.z);
            acc[6] += bl(a.w) + bl(b.w) + bl(d.w) + bl(e.w);
            acc[7] += bh(a.w) + bh(b.w) + bh(d.w) + bh(e.w);
        }
        float inv = 1.0f / fmaxf((float)dn, 1.0f);
        float rr[8] = { bl(r.x), bh(r.x), bl(r.y), bh(r.y),
                        bl(r.z), bh(r.z), bl(r.w), bh(r.w) };
#pragma unroll
        for (int j = 0; j < 8; ++j)
            shh[(c * 8 + j) * 65 + loc] = fmaxf(acc[j] * inv + rr[j] + sb1[c * 8 + j], 0.f);
    }
    __syncthreads();

    if (valid) {
        float accp[4], accr[4];
#pragma unroll
        for (int j = 0; j < 4; ++j) { accp[j] = 0.f; accr[j] = 0.f; }
#pragma unroll
        for (int k2i = 0; k2i < 32; ++k2i) {
            float hk = shh[k2i * 65 + loc];
#pragma unroll
            for (int j = 0; j < 4; ++j) {
                accp[j] += hk * sW2l[k2i * 16 + c * 4 + j];
                accr[j] += hk * sW2r[k2i * 16 + c * 4 + j];
            }
        }
        uint2 up, ur;
        up.x = pack2(accp[0], accp[1]); up.y = pack2(accp[2], accp[3]);
        ur.x = pack2(accr[0], accr[1]); ur.y = pack2(accr[2], accr[3]);
        reinterpret_cast<uint2*>(P2)[(size_t)n * 4 + c] = up;
        reinterpret_cast<uint2*>(R2)[(size_t)n * 4 + c] = ur;
    } else if (n == NN) {                       // zero row for layer-2 pads
        uint2 z = make_uint2(0, 0);
        reinterpret_cast<uint2*>(P2)[(size_t)NN * 4 + c] = z;
        reinterpret_cast<uint2*>(R2)[(size_t)NN * 4 + c] = z;
    }
}

// ---- K4: layer2 gather (unroll-2x4) fused with final head -------------------
__global__ __launch_bounds__(256) void gather2_kernel(
    const int* __restrict__ rowstart, const int* __restrict__ deg,
    const int* __restrict__ csr_src,
    const __hip_bfloat16* __restrict__ P2,
    const __hip_bfloat16* __restrict__ R2,
    const float* __restrict__ b2,       // [16]
    const float* __restrict__ Wlin,     // [16,2]
    const float* __restrict__ blin,     // [2]
    float* __restrict__ out)            // [NN,2]
{
    __shared__ float sb[16], sW[32], sbl[2];
    if (threadIdx.x < 16) sb[threadIdx.x] = b2[threadIdx.x];
    else if (threadIdx.x < 48) sW[threadIdx.x - 16] = Wlin[threadIdx.x - 16];
    else if (threadIdx.x < 50) sbl[threadIdx.x - 48] = blin[threadIdx.x - 48];
    __syncthreads();
    int t = blockIdx.x * 256 + threadIdx.x;
    int n = t >> 1, c = t & 1;
    if (n >= NN) return;
    int start = rowstart[n], dn = deg[n];
    int pv4 = ((dn + 3) & ~3) >> 2;

    const uint4* prow = reinterpret_cast<const uint4*>(P2);
    const int4* cp4 = reinterpret_cast<const int4*>(csr_src + start);
    uint4 r = reinterpret_cast<const uint4*>(R2)[(size_t)n * 2 + c]; // hoisted
    float acc[8];
#pragma unroll
    for (int j = 0; j < 8; ++j) acc[j] = 0.f;
    int k = 0;
    int4 sA = cp4[0];
    int4 sB = cp4[1];
    for (; k + 1 < pv4; k += 2) {
        int4 nA = cp4[k + 2];
        int4 nB = cp4[k + 3];
        uint4 a = prow[(size_t)sA.x * 2 + c];
        uint4 b = prow[(size_t)sA.y * 2 + c];
        uint4 d = prow[(size_t)sA.z * 2 + c];
        uint4 e = prow[(size_t)sA.w * 2 + c];
        uint4 f = prow[(size_t)sB.x * 2 + c];
        uint4 g = prow[(size_t)sB.y * 2 + c];
        uint4 h = prow[(size_t)sB.z * 2 + c];
        uint4 m = prow[(size_t)sB.w * 2 + c];
        acc[0] += bl(a.x) + bl(b.x) + bl(d.x) + bl(e.x)
                + bl(f.x) + bl(g.x) + bl(h.x) + bl(m.x);
        acc[1] += bh(a.x) + bh(b.x) + bh(d.x) + bh(e.x)
                + bh(f.x) + bh(g.x) + bh(h.x) + bh(m.x);
        acc[2] += bl(a.y) + bl(b.y) + bl(d.y) + bl(e.y)
                + bl(f.y) + bl(g.y) + bl(h.y) + bl(m.y);
        acc[3] += bh(a.y) + bh(b.y) + bh(d.y) + bh(e.y)
                + bh(f.y) + bh(g.y) + bh(h.y) + bh(m.y);
        acc[4] += bl(a.z) + bl(b.z) + bl(d.z) + bl(e.z)
                + bl(f.z) + bl(g.z) + bl(h.z) + bl(m.z);
        acc[5] += bh(a.z) + bh(b.z) + bh(d.z) + bh(e.z)
                + bh(f.z) + bh(g.z) + bh(h.z) + bh(m.z);
        acc[6] += bl(a.w) + bl(b.w) + bl(d.w) + bl(e.w)
                + bl(f.w) + bl(g.w) + bl(h.w) + bl(m.w);
        acc[7] += bh(a.w) + bh(b.w) + bh(d.w) + bh(e.w)
                + bh(f.w) + bh(g.w) + bh(h.w) + bh(m.w);
        sA = nA; sB = nB;
    }
    if (k < pv4) {                          // odd tail: one quad
        uint4 a = prow[(size_t)sA.x * 2 + c];
        uint4 b = prow[(size_t)sA.y * 2 + c];
        uint4 d = prow[(size_t)sA.z * 2 + c];
        uint4 e = prow[(size_t)sA.w * 2 + c];
        acc[0] += bl(a.x) + bl(b.x) + bl(d.x) + bl(e.x);
        acc[1] += bh(a.x) + bh(b.x) + bh(d.x) + bh(e.x);
        acc[2] += bl(a.y) + bl(b.y) + bl(d.y) + bl(e.y);
        acc[3] += bh(a.y) + bh(b.y) + bh(d.y) + bh(e.y);
        acc[4] += bl(a.z) + bl(b.z) + bl(d.z) + bl(e.z);
        acc[5] += bh(a.z) + bh(b.z) + bh(d.z) + bh(e.z);
        acc[6] += bl(a.w) + bl(b.w) + bl(d.w) + bl(e.w);
        acc[7] += bh(a.w) + bh(b.w) + bh(d.w) + bh(e.w);
    }
    float inv = 1.0f / fmaxf((float)dn, 1.0f);
    float rr[8] = { bl(r.x), bh(r.x), bl(r.y), bh(r.y),
                    bl(r.z), bh(r.z), bl(r.w), bh(r.w) };
    float o0 = 0.f, o1 = 0.f;
#pragma unroll
    for (int j = 0; j < 8; ++j) {
        int kk = c * 8 + j;
        float hv = fmaxf(acc[j] * inv + rr[j] + sb[kk], 0.f);
        o0 += hv * sW[kk * 2];
        o1 += hv * sW[kk * 2 + 1];
    }
    o0 += __shfl_xor(o0, 1, 64);
    o1 += __shfl_xor(o1, 1, 64);
    if (c == 0)
        reinterpret_cast<float2*>(out)[n] = make_float2(o0 + sbl[0], o1 + sbl[1]);
}

extern "C" void kernel_launch(void* const* d_in, const int* in_sizes, int n_in,
                              void* d_out, int out_size, void* d_ws, size_t ws_size,
                              hipStream_t stream)
{
    const float* x    = (const float*)d_in[0];
    const int*   ei   = (const int*)d_in[1];
    const float* W1l  = (const float*)d_in[2];
    const float* W1r  = (const float*)d_in[3];
    const float* b1   = (const float*)d_in[4];
    const float* W2l  = (const float*)d_in[5];
    const float* W2r  = (const float*)d_in[6];
    const float* b2   = (const float*)d_in[7];
    const float* Wlin = (const float*)d_in[8];
    const float* blin = (const float*)d_in[9];
    float* out = (float*)d_out;

    // ---- workspace layout (bytes; ws_size = 256 MiB) ----
    char* wsb = (char*)d_ws;
    int*      bsize    = (int*)(wsb + 64);              // int[NB]
    int*      deg      = (int*)(wsb + 4096);            // int[N]
    int*      rowstart = (int*)(wsb + 404096);          // int[N]
    int*      csr_src  = (int*)(wsb + 804096);          // int[NB*SEG] 8.41 MB
    unsigned* bbuf     = (unsigned*)(wsb + 9300000);    // u32[NB*CAP] 7.21 MB
    __hip_bfloat16* p1 = (__hip_bfloat16*)(wsb + 16600000); // bf16[N+1,32]
    __hip_bfloat16* r1 = (__hip_bfloat16*)(wsb + 23100000); // bf16[N,32]
    __hip_bfloat16* p2 = (__hip_bfloat16*)(wsb + 29600000); // bf16[N+1,16]
    __hip_bfloat16* r2 = (__hip_bfloat16*)(wsb + 32900000); // bf16[N+1,16]

    dim3 blk(256);

    hipMemsetAsync(bsize, 0, NB * sizeof(int), stream);
    k1_kernel<<<NCH + NB1, blk, 0, stream>>>(x, W1l, W1r, ei, bsize, bbuf, p1, r1);
    k2_kernel<<<NB, dim3(1024), 0, stream>>>(bsize, bbuf, deg, rowstart, csr_src);
    gather1f_kernel<<<(NN + 1 + 63) / 64, blk, 0, stream>>>(
        rowstart, deg, csr_src, p1, r1, b1, W2l, W2r, p2, r2);
    gather2_kernel<<<(NN * 2 + 255) / 256, blk, 0, stream>>>(
        rowstart, deg, csr_src, p2, r2, b2, Wlin, blin, out);
}